// Round 1
// baseline (288.775 us; speedup 1.0000x reference)
//
#include <hip/hip_runtime.h>
#include <hip/hip_bf16.h>

// Sizes
#define HD   256
#define TT   32
#define MV   4096
#define LD_  24
#define LP_  12
#define LM_  20
#define MAXNZ 96

typedef _Float16 h2v __attribute__((ext_vector_type(2)));

__device__ __forceinline__ float fdot2(h2v a, h2v b, float c) {
#if __has_builtin(__builtin_amdgcn_fdot2)
  return __builtin_amdgcn_fdot2(a, b, c, false);
#else
  return c + (float)a[0] * (float)b[0] + (float)a[1] * (float)b[1];
#endif
}

// K1: seq = sum of embedding rows; GI[b][t][g] = bih[g] + sum_k wih[g,k]*seq[k]
__global__ __launch_bounds__(768) void k1_embed_gi(
    const int* __restrict__ dc, const int* __restrict__ pc,
    const float* __restrict__ demb, const float* __restrict__ pemb,
    const float* __restrict__ wih_d, const float* __restrict__ bih_d,
    const float* __restrict__ wih_p, const float* __restrict__ bih_p,
    float* __restrict__ GI)
{
  const int t = blockIdx.x, b = blockIdx.y;
  const int* codes = b ? pc : dc;
  const int L = b ? LP_ : LD_;
  const float* emb = b ? pemb : demb;
  const float* wih = b ? wih_p : wih_d;
  const float* bih = b ? bih_p : bih_d;
  __shared__ float s[HD];
  const int j = threadIdx.x;
  if (j < HD) {
    float acc = 0.f;
    for (int l = 0; l < L; ++l) acc += emb[(size_t)codes[t * L + l] * HD + j];
    s[j] = acc;
  }
  __syncthreads();
  const int g = j;
  float acc = bih[g];
  const float* wr = wih + (size_t)g * HD;
  for (int k = 0; k < HD; k += 4) {
    float4 w4 = *(const float4*)(wr + k);
    acc = fmaf(w4.x, s[k], acc);
    acc = fmaf(w4.y, s[k + 1], acc);
    acc = fmaf(w4.z, s[k + 2], acc);
    acc = fmaf(w4.w, s[k + 3], acc);
  }
  GI[((size_t)b * TT + t) * 768 + g] = acc;
}

// K2: sequential GRU, whh register-resident as packed f16, fdot2 inner product.
__global__ __launch_bounds__(768) void k2_gru(
    const float* __restrict__ GI,
    const float* __restrict__ whh_d, const float* __restrict__ bhh_d,
    const float* __restrict__ whh_p, const float* __restrict__ bhh_p,
    float* __restrict__ feats)
{
  const int b = blockIdx.x;
  const float* whh = b ? whh_p : whh_d;
  const float* bhh = b ? bhh_p : bhh_d;
  const float* gi = GI + (size_t)b * TT * 768;
  const int g = threadIdx.x;

  h2v w[128];
#pragma unroll
  for (int i = 0; i < 128; ++i) {
    float2 f = *(const float2*)(whh + (size_t)g * HD + 2 * i);
    h2v tv; tv[0] = (_Float16)f.x; tv[1] = (_Float16)f.y;
    w[i] = tv;
  }
  const float bh = bhh[g];

  __shared__ h2v hhv[128];      // h as packed f16
  __shared__ float h32[HD];     // h in f32 (exact carry)
  __shared__ float ghs[768];
  _Float16* hhs = (_Float16*)hhv;
  if (g < HD) { hhs[g] = (_Float16)0.f; h32[g] = 0.f; }
  __syncthreads();

  for (int t = 0; t < TT; ++t) {
    float d0 = 0.f, d1 = 0.f;
#pragma unroll
    for (int i = 0; i < 128; i += 2) {
      d0 = fdot2(w[i], hhv[i], d0);
      d1 = fdot2(w[i + 1], hhv[i + 1], d1);
    }
    ghs[g] = d0 + d1 + bh;
    __syncthreads();
    if (g < HD) {
      const float* git = gi + t * 768;
      float ir = git[g], iz = git[HD + g], inn = git[2 * HD + g];
      float hr = ghs[g], hz = ghs[HD + g], hn = ghs[2 * HD + g];
      float r = 1.f / (1.f + __expf(-(ir + hr)));
      float z = 1.f / (1.f + __expf(-(iz + hz)));
      float n = tanhf(inn + r * hn);
      float h2 = (1.f - z) * n + z * h32[g];
      h32[g] = h2;
      hhs[g] = (_Float16)h2;
      feats[(size_t)t * 512 + b * HD + g] = h2;
    }
    __syncthreads();
  }
}

// K2b: queries[t,j] = q_b[j] + sum_k relu(feats[t,k]) * q_w[k,j]
__global__ __launch_bounds__(256) void k2b_queries(
    const float* __restrict__ feats, const float* __restrict__ q_w,
    const float* __restrict__ q_b, float* __restrict__ queries)
{
  const int t = blockIdx.x, j = threadIdx.x;
  __shared__ float f[512];
  f[j] = fmaxf(feats[(size_t)t * 512 + j], 0.f);
  f[j + 256] = fmaxf(feats[(size_t)t * 512 + 256 + j], 0.f);
  __syncthreads();
  float acc = q_b[j];
  for (int k = 0; k < 512; ++k) acc = fmaf(f[k], q_w[(size_t)k * HD + j], acc);
  queries[(size_t)t * HD + j] = acc;
}

// K3: stream one adj row per block; extract sparse (col,val) deterministically,
// and compute h1[row,:] = relu(sum val * w1[col,:] + b1).
__global__ __launch_bounds__(256) void k3_scan(
    const float* __restrict__ adj_e, const float* __restrict__ adj_d,
    const float* __restrict__ w1_e, const float* __restrict__ b1_e,
    const float* __restrict__ w1_d, const float* __restrict__ b1_d,
    float* __restrict__ h1, int* __restrict__ cnt_g,
    int* __restrict__ cols_g, float* __restrict__ vals_g)
{
  const int r = blockIdx.x, b = blockIdx.y, j = threadIdx.x;
  const float* adj = (b ? adj_d : adj_e) + (size_t)r * MV;
  const float* w1 = b ? w1_d : w1_e;
  const float* b1 = b ? b1_d : b1_e;

  __shared__ int pA[256], pB[256];
  __shared__ int scols[MAXNZ];
  __shared__ float svals[MAXNZ];

  const float4* row4 = (const float4*)adj;
  float4 v0 = row4[0 * 256 + j];
  float4 v1 = row4[1 * 256 + j];
  float4 v2 = row4[2 * 256 + j];
  float4 v3 = row4[3 * 256 + j];
  int cl = 0;
  cl += (v0.x != 0.f) + (v0.y != 0.f) + (v0.z != 0.f) + (v0.w != 0.f);
  cl += (v1.x != 0.f) + (v1.y != 0.f) + (v1.z != 0.f) + (v1.w != 0.f);
  cl += (v2.x != 0.f) + (v2.y != 0.f) + (v2.z != 0.f) + (v2.w != 0.f);
  cl += (v3.x != 0.f) + (v3.y != 0.f) + (v3.z != 0.f) + (v3.w != 0.f);

  pA[j] = cl;
  __syncthreads();
  int* src = pA; int* dst = pB;
  for (int ofs = 1; ofs < 256; ofs <<= 1) {
    dst[j] = src[j] + (j >= ofs ? src[j - ofs] : 0);
    __syncthreads();
    int* tmp = src; src = dst; dst = tmp;
  }
  const int total = src[255];
  int pos = src[j] - cl;  // exclusive prefix

#define EMIT(VV, CI, CE)                                        \
  { float val = (VV);                                           \
    if (val != 0.f) { if (pos < MAXNZ) { scols[pos] = (CI) * 1024 + 4 * j + (CE); svals[pos] = val; } ++pos; } }
  EMIT(v0.x, 0, 0) EMIT(v0.y, 0, 1) EMIT(v0.z, 0, 2) EMIT(v0.w, 0, 3)
  EMIT(v1.x, 1, 0) EMIT(v1.y, 1, 1) EMIT(v1.z, 1, 2) EMIT(v1.w, 1, 3)
  EMIT(v2.x, 2, 0) EMIT(v2.y, 2, 1) EMIT(v2.z, 2, 2) EMIT(v2.w, 2, 3)
  EMIT(v3.x, 3, 0) EMIT(v3.y, 3, 1) EMIT(v3.z, 3, 2) EMIT(v3.w, 3, 3)
#undef EMIT
  __syncthreads();

  const int n = total > MAXNZ ? MAXNZ : total;
  float acc = b1[j];
  for (int k = 0; k < n; ++k)
    acc = fmaf(svals[k], w1[(size_t)scols[k] * HD + j], acc);

  const size_t rowg = (size_t)b * MV + r;
  h1[rowg * HD + j] = fmaxf(acc, 0.f);
  if (j == 0) cnt_g[rowg] = n;
  if (j < n) {
    cols_g[rowg * MAXNZ + j] = scols[j];
    vals_g[rowg * MAXNZ + j] = svals[j];
  }
}

// K4: z = h1 @ w2  (per matrix), 16 rows per block
__global__ __launch_bounds__(256) void k4_z(
    const float* __restrict__ h1, const float* __restrict__ w2_e,
    const float* __restrict__ w2_d, float* __restrict__ zz)
{
  const int blk = blockIdx.x, b = blockIdx.y, j = threadIdx.x;
  const float* w2 = b ? w2_d : w2_e;
  const float* h1b = h1 + (size_t)b * MV * HD + (size_t)blk * 16 * HD;
  __shared__ float tile[16][HD];
  for (int r = 0; r < 16; ++r) tile[r][j] = h1b[r * HD + j];
  __syncthreads();
  float acc[16];
#pragma unroll
  for (int r = 0; r < 16; ++r) acc[r] = 0.f;
  for (int k = 0; k < HD; ++k) {
    float w = w2[(size_t)k * HD + j];
#pragma unroll
    for (int r = 0; r < 16; ++r) acc[r] = fmaf(tile[r][k], w, acc[r]);
  }
  float* zb = zz + (size_t)b * MV * HD + (size_t)blk * 16 * HD;
  for (int r = 0; r < 16; ++r) zb[r * HD + j] = acc[r];
}

// K5: prior[r,:] = (sparse_ehr(r)@z_e + b2_e) - inter*(sparse_ddi(r)@z_d + b2_d);
//     s1[r] = query . prior[r,:]
__global__ __launch_bounds__(256) void k5_prior(
    const float* __restrict__ zz, const int* __restrict__ cnt_g,
    const int* __restrict__ cols_g, const float* __restrict__ vals_g,
    const float* __restrict__ b2_e, const float* __restrict__ b2_d,
    const float* __restrict__ inter, const float* __restrict__ queries,
    float* __restrict__ prior, float* __restrict__ s1)
{
  const int r = blockIdx.x, j = threadIdx.x;
  __shared__ float red[256];
  float acc_e = b2_e[j];
  {
    const int ne = cnt_g[r];
    const int* ce = cols_g + (size_t)r * MAXNZ;
    const float* ve = vals_g + (size_t)r * MAXNZ;
    for (int k = 0; k < ne; ++k)
      acc_e = fmaf(ve[k], zz[(size_t)ce[k] * HD + j], acc_e);
  }
  float acc_d = b2_d[j];
  {
    const int nd = cnt_g[MV + r];
    const int* cd = cols_g + (size_t)(MV + r) * MAXNZ;
    const float* vd = vals_g + (size_t)(MV + r) * MAXNZ;
    const float* zd = zz + (size_t)MV * HD;
    for (int k = 0; k < nd; ++k)
      acc_d = fmaf(vd[k], zd[(size_t)cd[k] * HD + j], acc_d);
  }
  const float pr = acc_e - inter[0] * acc_d;
  prior[(size_t)r * HD + j] = pr;
  red[j] = queries[31 * HD + j] * pr;
  __syncthreads();
  for (int s = 128; s > 0; s >>= 1) {
    if (j < s) red[j] += red[j + s];
    __syncthreads();
  }
  if (j == 0) s1[r] = red[0];
}

// K6a: w_emb = softmax(s1) over 4096; visit_w = softmax(query . queries[t<31])
__global__ __launch_bounds__(1024) void k6a_softmax(
    const float* __restrict__ s1, const float* __restrict__ queries,
    float* __restrict__ w_emb, float* __restrict__ visw)
{
  const int j = threadIdx.x;
  __shared__ float red[1024];
  __shared__ float s2[31];
  float m = -1e30f;
  for (int i = j; i < MV; i += 1024) m = fmaxf(m, s1[i]);
  red[j] = m;
  __syncthreads();
  for (int s = 512; s > 0; s >>= 1) {
    if (j < s) red[j] = fmaxf(red[j], red[j + s]);
    __syncthreads();
  }
  const float mx = red[0];
  __syncthreads();
  float sum = 0.f;
  for (int i = j; i < MV; i += 1024) sum += __expf(s1[i] - mx);
  red[j] = sum;
  __syncthreads();
  for (int s = 512; s > 0; s >>= 1) {
    if (j < s) red[j] += red[j + s];
    __syncthreads();
  }
  const float inv = 1.f / red[0];
  for (int i = j; i < MV; i += 1024) w_emb[i] = __expf(s1[i] - mx) * inv;

  if (j < 31) {
    float acc = 0.f;
    for (int k = 0; k < HD; ++k)
      acc = fmaf(queries[31 * HD + k], queries[(size_t)j * HD + k], acc);
    s2[j] = acc;
  }
  __syncthreads();
  if (j == 0) {
    float mm = -1e30f;
    for (int t = 0; t < 31; ++t) mm = fmaxf(mm, s2[t]);
    float ss = 0.f;
    for (int t = 0; t < 31; ++t) ss += __expf(s2[t] - mm);
    const float is = 1.f / ss;
    for (int t = 0; t < 31; ++t) visw[t] = __expf(s2[t] - mm) * is;
  }
}

// K6b: wv[m] = sum_t visit_w[t] * [m in med_codes[t]]  (set semantics)
__global__ __launch_bounds__(1024) void k6b_wv(
    const int* __restrict__ med, const float* __restrict__ visw,
    float* __restrict__ wv)
{
  __shared__ int mc[31 * LM_];
  __shared__ float vw[31];
  const int j = threadIdx.x;
  if (j < 31 * LM_) mc[j] = med[j];
  if (j < 31) vw[j] = visw[j];
  __syncthreads();
  const int m = blockIdx.x * 1024 + j;
  float acc = 0.f;
  for (int t = 0; t < 31; ++t) {
    bool found = false;
#pragma unroll
    for (int l = 0; l < LM_; ++l) found = found || (mc[t * LM_ + l] == m);
    if (found) acc += vw[t];
  }
  wv[m] = acc;
}

// K7: out[r,j] = w_emb[r]*(prior[r,:].Wa[:,j]) + wv[r]*(prior[r,:].Wb[:,j]) + proj_b[j]
__global__ __launch_bounds__(256) void k7_out(
    const float* __restrict__ prior, const float* __restrict__ w_emb,
    const float* __restrict__ wv, const float* __restrict__ proj_w,
    const float* __restrict__ proj_b, float* __restrict__ out)
{
  const int blk = blockIdx.x, j = threadIdx.x;
  const int r0 = blk * 16;
  __shared__ float tile[16][HD];
  __shared__ float we[16], wvv[16];
  for (int r = 0; r < 16; ++r) tile[r][j] = prior[(size_t)(r0 + r) * HD + j];
  if (j < 16) { we[j] = w_emb[r0 + j]; wvv[j] = wv[r0 + j]; }
  __syncthreads();
  float accA[16], accB[16];
#pragma unroll
  for (int r = 0; r < 16; ++r) { accA[r] = 0.f; accB[r] = 0.f; }
  for (int k = 0; k < HD; ++k) {
    const float wa = proj_w[(size_t)k * HD + j];
    const float wb = proj_w[(size_t)(k + HD) * HD + j];
#pragma unroll
    for (int r = 0; r < 16; ++r) {
      const float p = tile[r][k];
      accA[r] = fmaf(p, wa, accA[r]);
      accB[r] = fmaf(p, wb, accB[r]);
    }
  }
  const float pb = proj_b[j];
  for (int r = 0; r < 16; ++r)
    out[(size_t)(r0 + r) * HD + j] = we[r] * accA[r] + wvv[r] * accB[r] + pb;
}

extern "C" void kernel_launch(void* const* d_in, const int* in_sizes, int n_in,
                              void* d_out, int out_size, void* d_ws, size_t ws_size,
                              hipStream_t stream) {
  const int* diag_codes = (const int*)d_in[0];
  const int* proc_codes = (const int*)d_in[1];
  const int* med_codes  = (const int*)d_in[2];
  const float* diag_emb = (const float*)d_in[3];
  const float* proc_emb = (const float*)d_in[4];
  const float* wih_d = (const float*)d_in[5];
  const float* whh_d = (const float*)d_in[6];
  const float* bih_d = (const float*)d_in[7];
  const float* bhh_d = (const float*)d_in[8];
  const float* wih_p = (const float*)d_in[9];
  const float* whh_p = (const float*)d_in[10];
  const float* bih_p = (const float*)d_in[11];
  const float* bhh_p = (const float*)d_in[12];
  const float* q_w = (const float*)d_in[13];
  const float* q_b = (const float*)d_in[14];
  const float* adj_ehr = (const float*)d_in[15];
  const float* adj_ddi = (const float*)d_in[16];
  const float* w1_ehr = (const float*)d_in[17];
  const float* b1_ehr = (const float*)d_in[18];
  const float* w2_ehr = (const float*)d_in[19];
  const float* b2_ehr = (const float*)d_in[20];
  const float* w1_ddi = (const float*)d_in[21];
  const float* b1_ddi = (const float*)d_in[22];
  const float* w2_ddi = (const float*)d_in[23];
  const float* b2_ddi = (const float*)d_in[24];
  const float* inter = (const float*)d_in[25];
  const float* proj_w = (const float*)d_in[26];
  const float* proj_b = (const float*)d_in[27];
  float* out = (float*)d_out;

  float* ws = (float*)d_ws;
  size_t off = 0;
  float* GI      = ws + off; off += 2 * TT * 768;        // 49152
  float* feats   = ws + off; off += TT * 512;            // 16384
  float* queries = ws + off; off += TT * HD;             // 8192
  float* h1      = ws + off; off += 2 * (size_t)MV * HD; // 2M
  float* zz      = ws + off; off += 2 * (size_t)MV * HD; // 2M
  float* prior   = ws + off; off += (size_t)MV * HD;     // 1M
  float* s1      = ws + off; off += MV;
  float* w_emb   = ws + off; off += MV;
  float* visw    = ws + off; off += 32;
  float* wv      = ws + off; off += MV;
  int*   cnt_g   = (int*)(ws + off); off += 2 * MV;
  int*   cols_g  = (int*)(ws + off); off += 2 * (size_t)MV * MAXNZ;
  float* vals_g  = ws + off; off += 2 * (size_t)MV * MAXNZ;
  (void)ws_size; (void)in_sizes; (void)n_in; (void)out_size;

  k1_embed_gi<<<dim3(TT, 2), 768, 0, stream>>>(diag_codes, proc_codes, diag_emb,
      proc_emb, wih_d, bih_d, wih_p, bih_p, GI);
  k2_gru<<<2, 768, 0, stream>>>(GI, whh_d, bhh_d, whh_p, bhh_p, feats);
  k2b_queries<<<TT, 256, 0, stream>>>(feats, q_w, q_b, queries);
  k3_scan<<<dim3(MV, 2), 256, 0, stream>>>(adj_ehr, adj_ddi, w1_ehr, b1_ehr,
      w1_ddi, b1_ddi, h1, cnt_g, cols_g, vals_g);
  k4_z<<<dim3(MV / 16, 2), 256, 0, stream>>>(h1, w2_ehr, w2_ddi, zz);
  k5_prior<<<MV, 256, 0, stream>>>(zz, cnt_g, cols_g, vals_g, b2_ehr, b2_ddi,
      inter, queries, prior, s1);
  k6a_softmax<<<1, 1024, 0, stream>>>(s1, queries, w_emb, visw);
  k6b_wv<<<MV / 1024, 1024, 0, stream>>>(med_codes, visw, wv);
  k7_out<<<MV / 16, 256, 0, stream>>>(prior, w_emb, wv, proj_w, proj_b, out);
}

// Round 2
// 287.212 us; speedup vs baseline: 1.0054x; 1.0054x over previous
//
#include <hip/hip_runtime.h>
#include <hip/hip_bf16.h>

// Sizes
#define HD   256
#define TT   32
#define MV   4096
#define LD_  24
#define LP_  12
#define LM_  20
#define MAXNZ 96

typedef _Float16 h2v __attribute__((ext_vector_type(2)));
typedef _Float16 h8  __attribute__((ext_vector_type(8)));

__device__ __forceinline__ float fdot2(h2v a, h2v b, float c) {
#if __has_builtin(__builtin_amdgcn_fdot2)
  return __builtin_amdgcn_fdot2(a, b, c, false);
#else
  return c + (float)a[0] * (float)b[0] + (float)a[1] * (float)b[1];
#endif
}

// K1: seq = sum of embedding rows; GI[b][t][g] = bih[g] + sum_k wih[g,k]*seq[k]
__global__ __launch_bounds__(768) void k1_embed_gi(
    const int* __restrict__ dc, const int* __restrict__ pc,
    const float* __restrict__ demb, const float* __restrict__ pemb,
    const float* __restrict__ wih_d, const float* __restrict__ bih_d,
    const float* __restrict__ wih_p, const float* __restrict__ bih_p,
    float* __restrict__ GI)
{
  const int t = blockIdx.x, b = blockIdx.y;
  const int* codes = b ? pc : dc;
  const int L = b ? LP_ : LD_;
  const float* emb = b ? pemb : demb;
  const float* wih = b ? wih_p : wih_d;
  const float* bih = b ? bih_p : bih_d;
  __shared__ float s[HD];
  const int j = threadIdx.x;
  if (j < HD) {
    float acc = 0.f;
    for (int l = 0; l < L; ++l) acc += emb[(size_t)codes[t * L + l] * HD + j];
    s[j] = acc;
  }
  __syncthreads();
  const int g = j;
  float acc = bih[g];
  const float* wr = wih + (size_t)g * HD;
  for (int k = 0; k < HD; k += 4) {
    float4 w4 = *(const float4*)(wr + k);
    acc = fmaf(w4.x, s[k], acc);
    acc = fmaf(w4.y, s[k + 1], acc);
    acc = fmaf(w4.z, s[k + 2], acc);
    acc = fmaf(w4.w, s[k + 3], acc);
  }
  GI[((size_t)b * TT + t) * 768 + g] = acc;
}

// K2: sequential GRU. whh register-resident as packed f16 (128 VGPRs), no spill:
// __launch_bounds__(768,3) => 3 waves/EU min => ~168 VGPR budget.
// h read from LDS as 16B h8 chunks; GI gate inputs prefetched per step (hidden
// under the ~768-cycle dot loop); 4 independent accumulator chains.
__global__ __launch_bounds__(768, 3) void k2_gru(
    const float* __restrict__ GI,
    const float* __restrict__ whh_d, const float* __restrict__ bhh_d,
    const float* __restrict__ whh_p, const float* __restrict__ bhh_p,
    float* __restrict__ feats)
{
  const int b = blockIdx.x;
  const float* whh = b ? whh_p : whh_d;
  const float* bhh = b ? bhh_p : bhh_d;
  const float* gi = GI + (size_t)b * TT * 768;
  const int g = threadIdx.x;

  h2v w[128];
#pragma unroll
  for (int i = 0; i < 128; ++i) {
    float2 f = *(const float2*)(whh + (size_t)g * HD + 2 * i);
    h2v tv; tv[0] = (_Float16)f.x; tv[1] = (_Float16)f.y;
    w[i] = tv;
  }
  const float bh = bhh[g];

  __shared__ h8 hh8[32];        // h as packed f16, 16B-granular
  __shared__ float h32[HD];     // h in f32 (exact carry)
  __shared__ float ghs[768];
  _Float16* hhs = (_Float16*)hh8;
  if (g < HD) { hhs[g] = (_Float16)0.f; h32[g] = 0.f; }
  __syncthreads();

  const int gq = g & 255;
  for (int t = 0; t < TT; ++t) {
    // prefetch gate inputs (independent of h) — hides L2 latency under dots
    const float* git = gi + t * 768;
    float ir = git[gq], iz = git[HD + gq], inn = git[2 * HD + gq];

    float d0 = 0.f, d1 = 0.f, d2 = 0.f, d3 = 0.f;
#pragma unroll
    for (int i = 0; i < 32; ++i) {
      union { h8 v; h2v p[4]; } u;
      u.v = hh8[i];
      d0 = fdot2(w[4 * i + 0], u.p[0], d0);
      d1 = fdot2(w[4 * i + 1], u.p[1], d1);
      d2 = fdot2(w[4 * i + 2], u.p[2], d2);
      d3 = fdot2(w[4 * i + 3], u.p[3], d3);
    }
    ghs[g] = (d0 + d1) + (d2 + d3) + bh;
    __syncthreads();
    if (g < HD) {
      float hr = ghs[g], hz = ghs[HD + g], hn = ghs[2 * HD + g];
      float r = 1.f / (1.f + __expf(-(ir + hr)));
      float z = 1.f / (1.f + __expf(-(iz + hz)));
      float n = tanhf(inn + r * hn);
      float h2 = (1.f - z) * n + z * h32[g];
      h32[g] = h2;
      hhs[g] = (_Float16)h2;
      feats[(size_t)t * 512 + b * HD + g] = h2;
    }
    __syncthreads();
  }
}

// K2b: queries[t,j] = q_b[j] + sum_k relu(feats[t,k]) * q_w[k,j]
__global__ __launch_bounds__(256) void k2b_queries(
    const float* __restrict__ feats, const float* __restrict__ q_w,
    const float* __restrict__ q_b, float* __restrict__ queries)
{
  const int t = blockIdx.x, j = threadIdx.x;
  __shared__ float f[512];
  f[j] = fmaxf(feats[(size_t)t * 512 + j], 0.f);
  f[j + 256] = fmaxf(feats[(size_t)t * 512 + 256 + j], 0.f);
  __syncthreads();
  float acc = q_b[j];
  for (int k = 0; k < 512; ++k) acc = fmaf(f[k], q_w[(size_t)k * HD + j], acc);
  queries[(size_t)t * HD + j] = acc;
}

// K3: stream one adj row per block; extract sparse (col,val) deterministically,
// and compute h1[row,:] = relu(sum val * w1[col,:] + b1).
__global__ __launch_bounds__(256) void k3_scan(
    const float* __restrict__ adj_e, const float* __restrict__ adj_d,
    const float* __restrict__ w1_e, const float* __restrict__ b1_e,
    const float* __restrict__ w1_d, const float* __restrict__ b1_d,
    float* __restrict__ h1, int* __restrict__ cnt_g,
    int* __restrict__ cols_g, float* __restrict__ vals_g)
{
  const int r = blockIdx.x, b = blockIdx.y, j = threadIdx.x;
  const float* adj = (b ? adj_d : adj_e) + (size_t)r * MV;
  const float* w1 = b ? w1_d : w1_e;
  const float* b1 = b ? b1_d : b1_e;

  __shared__ int pA[256], pB[256];
  __shared__ int scols[MAXNZ];
  __shared__ float svals[MAXNZ];

  const float4* row4 = (const float4*)adj;
  float4 v0 = row4[0 * 256 + j];
  float4 v1 = row4[1 * 256 + j];
  float4 v2 = row4[2 * 256 + j];
  float4 v3 = row4[3 * 256 + j];
  int cl = 0;
  cl += (v0.x != 0.f) + (v0.y != 0.f) + (v0.z != 0.f) + (v0.w != 0.f);
  cl += (v1.x != 0.f) + (v1.y != 0.f) + (v1.z != 0.f) + (v1.w != 0.f);
  cl += (v2.x != 0.f) + (v2.y != 0.f) + (v2.z != 0.f) + (v2.w != 0.f);
  cl += (v3.x != 0.f) + (v3.y != 0.f) + (v3.z != 0.f) + (v3.w != 0.f);

  pA[j] = cl;
  __syncthreads();
  int* src = pA; int* dst = pB;
  for (int ofs = 1; ofs < 256; ofs <<= 1) {
    dst[j] = src[j] + (j >= ofs ? src[j - ofs] : 0);
    __syncthreads();
    int* tmp = src; src = dst; dst = tmp;
  }
  const int total = src[255];
  int pos = src[j] - cl;  // exclusive prefix

#define EMIT(VV, CI, CE)                                        \
  { float val = (VV);                                           \
    if (val != 0.f) { if (pos < MAXNZ) { scols[pos] = (CI) * 1024 + 4 * j + (CE); svals[pos] = val; } ++pos; } }
  EMIT(v0.x, 0, 0) EMIT(v0.y, 0, 1) EMIT(v0.z, 0, 2) EMIT(v0.w, 0, 3)
  EMIT(v1.x, 1, 0) EMIT(v1.y, 1, 1) EMIT(v1.z, 1, 2) EMIT(v1.w, 1, 3)
  EMIT(v2.x, 2, 0) EMIT(v2.y, 2, 1) EMIT(v2.z, 2, 2) EMIT(v2.w, 2, 3)
  EMIT(v3.x, 3, 0) EMIT(v3.y, 3, 1) EMIT(v3.z, 3, 2) EMIT(v3.w, 3, 3)
#undef EMIT
  __syncthreads();

  const int n = total > MAXNZ ? MAXNZ : total;
  float acc = b1[j];
  for (int k = 0; k < n; ++k)
    acc = fmaf(svals[k], w1[(size_t)scols[k] * HD + j], acc);

  const size_t rowg = (size_t)b * MV + r;
  h1[rowg * HD + j] = fmaxf(acc, 0.f);
  if (j == 0) cnt_g[rowg] = n;
  if (j < n) {
    cols_g[rowg * MAXNZ + j] = scols[j];
    vals_g[rowg * MAXNZ + j] = svals[j];
  }
}

// K4: z = h1 @ w2  (per matrix), 16 rows per block, float4 LDS tile reads
__global__ __launch_bounds__(256) void k4_z(
    const float* __restrict__ h1, const float* __restrict__ w2_e,
    const float* __restrict__ w2_d, float* __restrict__ zz)
{
  const int blk = blockIdx.x, b = blockIdx.y, j = threadIdx.x;
  const float* w2 = b ? w2_d : w2_e;
  const float* h1b = h1 + (size_t)b * MV * HD + (size_t)blk * 16 * HD;
  __shared__ float tile[16][HD];
  for (int r = 0; r < 16; ++r) tile[r][j] = h1b[r * HD + j];
  __syncthreads();
  float acc[16];
#pragma unroll
  for (int r = 0; r < 16; ++r) acc[r] = 0.f;
  for (int k = 0; k < HD; k += 4) {
    float wa = w2[(size_t)(k + 0) * HD + j];
    float wb = w2[(size_t)(k + 1) * HD + j];
    float wc = w2[(size_t)(k + 2) * HD + j];
    float wd = w2[(size_t)(k + 3) * HD + j];
#pragma unroll
    for (int r = 0; r < 16; ++r) {
      float4 tv = *(const float4*)&tile[r][k];
      acc[r] = fmaf(tv.x, wa, acc[r]);
      acc[r] = fmaf(tv.y, wb, acc[r]);
      acc[r] = fmaf(tv.z, wc, acc[r]);
      acc[r] = fmaf(tv.w, wd, acc[r]);
    }
  }
  float* zb = zz + (size_t)b * MV * HD + (size_t)blk * 16 * HD;
  for (int r = 0; r < 16; ++r) zb[r * HD + j] = acc[r];
}

// K5: prior[r,:] = (sparse_ehr(r)@z_e + b2_e) - inter*(sparse_ddi(r)@z_d + b2_d);
//     s1[r] = query . prior[r,:]
__global__ __launch_bounds__(256) void k5_prior(
    const float* __restrict__ zz, const int* __restrict__ cnt_g,
    const int* __restrict__ cols_g, const float* __restrict__ vals_g,
    const float* __restrict__ b2_e, const float* __restrict__ b2_d,
    const float* __restrict__ inter, const float* __restrict__ queries,
    float* __restrict__ prior, float* __restrict__ s1)
{
  const int r = blockIdx.x, j = threadIdx.x;
  __shared__ float red[256];
  float acc_e = b2_e[j];
  {
    const int ne = cnt_g[r];
    const int* ce = cols_g + (size_t)r * MAXNZ;
    const float* ve = vals_g + (size_t)r * MAXNZ;
    for (int k = 0; k < ne; ++k)
      acc_e = fmaf(ve[k], zz[(size_t)ce[k] * HD + j], acc_e);
  }
  float acc_d = b2_d[j];
  {
    const int nd = cnt_g[MV + r];
    const int* cd = cols_g + (size_t)(MV + r) * MAXNZ;
    const float* vd = vals_g + (size_t)(MV + r) * MAXNZ;
    const float* zd = zz + (size_t)MV * HD;
    for (int k = 0; k < nd; ++k)
      acc_d = fmaf(vd[k], zd[(size_t)cd[k] * HD + j], acc_d);
  }
  const float pr = acc_e - inter[0] * acc_d;
  prior[(size_t)r * HD + j] = pr;
  red[j] = queries[31 * HD + j] * pr;
  __syncthreads();
  for (int s = 128; s > 0; s >>= 1) {
    if (j < s) red[j] += red[j + s];
    __syncthreads();
  }
  if (j == 0) s1[r] = red[0];
}

// K6a: w_emb = softmax(s1) over 4096; visit_w = softmax(query . queries[t<31])
__global__ __launch_bounds__(1024) void k6a_softmax(
    const float* __restrict__ s1, const float* __restrict__ queries,
    float* __restrict__ w_emb, float* __restrict__ visw)
{
  const int j = threadIdx.x;
  __shared__ float red[1024];
  __shared__ float s2[31];
  float m = -1e30f;
  for (int i = j; i < MV; i += 1024) m = fmaxf(m, s1[i]);
  red[j] = m;
  __syncthreads();
  for (int s = 512; s > 0; s >>= 1) {
    if (j < s) red[j] = fmaxf(red[j], red[j + s]);
    __syncthreads();
  }
  const float mx = red[0];
  __syncthreads();
  float sum = 0.f;
  for (int i = j; i < MV; i += 1024) sum += __expf(s1[i] - mx);
  red[j] = sum;
  __syncthreads();
  for (int s = 512; s > 0; s >>= 1) {
    if (j < s) red[j] += red[j + s];
    __syncthreads();
  }
  const float inv = 1.f / red[0];
  for (int i = j; i < MV; i += 1024) w_emb[i] = __expf(s1[i] - mx) * inv;

  if (j < 31) {
    float acc = 0.f;
    for (int k = 0; k < HD; ++k)
      acc = fmaf(queries[31 * HD + k], queries[(size_t)j * HD + k], acc);
    s2[j] = acc;
  }
  __syncthreads();
  if (j == 0) {
    float mm = -1e30f;
    for (int t = 0; t < 31; ++t) mm = fmaxf(mm, s2[t]);
    float ss = 0.f;
    for (int t = 0; t < 31; ++t) ss += __expf(s2[t] - mm);
    const float is = 1.f / ss;
    for (int t = 0; t < 31; ++t) visw[t] = __expf(s2[t] - mm) * is;
  }
}

// K6b: wv[m] = sum_t visit_w[t] * [m in med_codes[t]]  (set semantics)
__global__ __launch_bounds__(1024) void k6b_wv(
    const int* __restrict__ med, const float* __restrict__ visw,
    float* __restrict__ wv)
{
  __shared__ int mc[31 * LM_];
  __shared__ float vw[31];
  const int j = threadIdx.x;
  if (j < 31 * LM_) mc[j] = med[j];
  if (j < 31) vw[j] = visw[j];
  __syncthreads();
  const int m = blockIdx.x * 1024 + j;
  float acc = 0.f;
  for (int t = 0; t < 31; ++t) {
    bool found = false;
#pragma unroll
    for (int l = 0; l < LM_; ++l) found = found || (mc[t * LM_ + l] == m);
    if (found) acc += vw[t];
  }
  wv[m] = acc;
}

// K7: out[r,j] = w_emb[r]*(prior[r,:].Wa[:,j]) + wv[r]*(prior[r,:].Wb[:,j]) + proj_b[j]
__global__ __launch_bounds__(256) void k7_out(
    const float* __restrict__ prior, const float* __restrict__ w_emb,
    const float* __restrict__ wv, const float* __restrict__ proj_w,
    const float* __restrict__ proj_b, float* __restrict__ out)
{
  const int blk = blockIdx.x, j = threadIdx.x;
  const int r0 = blk * 16;
  __shared__ float tile[16][HD];
  __shared__ float we[16], wvv[16];
  for (int r = 0; r < 16; ++r) tile[r][j] = prior[(size_t)(r0 + r) * HD + j];
  if (j < 16) { we[j] = w_emb[r0 + j]; wvv[j] = wv[r0 + j]; }
  __syncthreads();
  float accA[16], accB[16];
#pragma unroll
  for (int r = 0; r < 16; ++r) { accA[r] = 0.f; accB[r] = 0.f; }
  for (int k = 0; k < HD; k += 4) {
    float wa0 = proj_w[(size_t)(k + 0) * HD + j];
    float wa1 = proj_w[(size_t)(k + 1) * HD + j];
    float wa2 = proj_w[(size_t)(k + 2) * HD + j];
    float wa3 = proj_w[(size_t)(k + 3) * HD + j];
    float wb0 = proj_w[(size_t)(k + 0 + HD) * HD + j];
    float wb1 = proj_w[(size_t)(k + 1 + HD) * HD + j];
    float wb2 = proj_w[(size_t)(k + 2 + HD) * HD + j];
    float wb3 = proj_w[(size_t)(k + 3 + HD) * HD + j];
#pragma unroll
    for (int r = 0; r < 16; ++r) {
      float4 tv = *(const float4*)&tile[r][k];
      accA[r] = fmaf(tv.x, wa0, accA[r]);
      accA[r] = fmaf(tv.y, wa1, accA[r]);
      accA[r] = fmaf(tv.z, wa2, accA[r]);
      accA[r] = fmaf(tv.w, wa3, accA[r]);
      accB[r] = fmaf(tv.x, wb0, accB[r]);
      accB[r] = fmaf(tv.y, wb1, accB[r]);
      accB[r] = fmaf(tv.z, wb2, accB[r]);
      accB[r] = fmaf(tv.w, wb3, accB[r]);
    }
  }
  const float pb = proj_b[j];
  for (int r = 0; r < 16; ++r)
    out[(size_t)(r0 + r) * HD + j] = we[r] * accA[r] + wvv[r] * accB[r] + pb;
}

extern "C" void kernel_launch(void* const* d_in, const int* in_sizes, int n_in,
                              void* d_out, int out_size, void* d_ws, size_t ws_size,
                              hipStream_t stream) {
  const int* diag_codes = (const int*)d_in[0];
  const int* proc_codes = (const int*)d_in[1];
  const int* med_codes  = (const int*)d_in[2];
  const float* diag_emb = (const float*)d_in[3];
  const float* proc_emb = (const float*)d_in[4];
  const float* wih_d = (const float*)d_in[5];
  const float* whh_d = (const float*)d_in[6];
  const float* bih_d = (const float*)d_in[7];
  const float* bhh_d = (const float*)d_in[8];
  const float* wih_p = (const float*)d_in[9];
  const float* whh_p = (const float*)d_in[10];
  const float* bih_p = (const float*)d_in[11];
  const float* bhh_p = (const float*)d_in[12];
  const float* q_w = (const float*)d_in[13];
  const float* q_b = (const float*)d_in[14];
  const float* adj_ehr = (const float*)d_in[15];
  const float* adj_ddi = (const float*)d_in[16];
  const float* w1_ehr = (const float*)d_in[17];
  const float* b1_ehr = (const float*)d_in[18];
  const float* w2_ehr = (const float*)d_in[19];
  const float* b2_ehr = (const float*)d_in[20];
  const float* w1_ddi = (const float*)d_in[21];
  const float* b1_ddi = (const float*)d_in[22];
  const float* w2_ddi = (const float*)d_in[23];
  const float* b2_ddi = (const float*)d_in[24];
  const float* inter = (const float*)d_in[25];
  const float* proj_w = (const float*)d_in[26];
  const float* proj_b = (const float*)d_in[27];
  float* out = (float*)d_out;

  float* ws = (float*)d_ws;
  size_t off = 0;
  float* GI      = ws + off; off += 2 * TT * 768;        // 49152
  float* feats   = ws + off; off += TT * 512;            // 16384
  float* queries = ws + off; off += TT * HD;             // 8192
  float* h1      = ws + off; off += 2 * (size_t)MV * HD; // 2M
  float* zz      = ws + off; off += 2 * (size_t)MV * HD; // 2M
  float* prior   = ws + off; off += (size_t)MV * HD;     // 1M
  float* s1      = ws + off; off += MV;
  float* w_emb   = ws + off; off += MV;
  float* visw    = ws + off; off += 32;
  float* wv      = ws + off; off += MV;
  int*   cnt_g   = (int*)(ws + off); off += 2 * MV;
  int*   cols_g  = (int*)(ws + off); off += 2 * (size_t)MV * MAXNZ;
  float* vals_g  = ws + off; off += 2 * (size_t)MV * MAXNZ;
  (void)ws_size; (void)in_sizes; (void)n_in; (void)out_size;

  k1_embed_gi<<<dim3(TT, 2), 768, 0, stream>>>(diag_codes, proc_codes, diag_emb,
      proc_emb, wih_d, bih_d, wih_p, bih_p, GI);
  k2_gru<<<2, 768, 0, stream>>>(GI, whh_d, bhh_d, whh_p, bhh_p, feats);
  k2b_queries<<<TT, 256, 0, stream>>>(feats, q_w, q_b, queries);
  k3_scan<<<dim3(MV, 2), 256, 0, stream>>>(adj_ehr, adj_ddi, w1_ehr, b1_ehr,
      w1_ddi, b1_ddi, h1, cnt_g, cols_g, vals_g);
  k4_z<<<dim3(MV / 16, 2), 256, 0, stream>>>(h1, w2_ehr, w2_ddi, zz);
  k5_prior<<<MV, 256, 0, stream>>>(zz, cnt_g, cols_g, vals_g, b2_ehr, b2_ddi,
      inter, queries, prior, s1);
  k6a_softmax<<<1, 1024, 0, stream>>>(s1, queries, w_emb, visw);
  k6b_wv<<<MV / 1024, 1024, 0, stream>>>(med_codes, visw, wv);
  k7_out<<<MV / 16, 256, 0, stream>>>(prior, w_emb, wv, proj_w, proj_b, out);
}

// Round 3
// 252.890 us; speedup vs baseline: 1.1419x; 1.1357x over previous
//
#include <hip/hip_runtime.h>
#include <hip/hip_bf16.h>

// Sizes
#define HD   256
#define TT   32
#define MV   4096
#define LD_  24
#define LP_  12
#define LM_  20
#define MAXNZ 96

typedef _Float16 h2v __attribute__((ext_vector_type(2)));
typedef _Float16 h8  __attribute__((ext_vector_type(8)));

__device__ __forceinline__ float fdot2(h2v a, h2v b, float c) {
#if __has_builtin(__builtin_amdgcn_fdot2)
  return __builtin_amdgcn_fdot2(a, b, c, false);
#else
  return c + (float)a[0] * (float)b[0] + (float)a[1] * (float)b[1];
#endif
}

// K0: whh (f32, 768x256 row-major) -> f16, transposed chunk layout:
// wt[b][i][g] = h8 of whh[b][g][8i..8i+7]  (i in [0,32), g in [0,768))
// So k2's per-i loads are lane-coalesced (lane g -> consecutive 16B).
__global__ __launch_bounds__(768) void k0_cvt(
    const float* __restrict__ whh_d, const float* __restrict__ whh_p,
    h8* __restrict__ wt)
{
  const int i = blockIdx.x, b = blockIdx.y, g = threadIdx.x;
  const float* whh = b ? whh_p : whh_d;
  const float* src = whh + (size_t)g * HD + 8 * i;
  h8 v;
#pragma unroll
  for (int e = 0; e < 8; ++e) v[e] = (_Float16)src[e];
  wt[((size_t)b * 32 + i) * 768 + g] = v;
}

// K1: seq = sum of embedding rows; GI[b][t][g] = bih[g] + sum_k wih[g,k]*seq[k]
__global__ __launch_bounds__(768) void k1_embed_gi(
    const int* __restrict__ dc, const int* __restrict__ pc,
    const float* __restrict__ demb, const float* __restrict__ pemb,
    const float* __restrict__ wih_d, const float* __restrict__ bih_d,
    const float* __restrict__ wih_p, const float* __restrict__ bih_p,
    float* __restrict__ GI)
{
  const int t = blockIdx.x, b = blockIdx.y;
  const int* codes = b ? pc : dc;
  const int L = b ? LP_ : LD_;
  const float* emb = b ? pemb : demb;
  const float* wih = b ? wih_p : wih_d;
  const float* bih = b ? bih_p : bih_d;
  __shared__ float s[HD];
  const int j = threadIdx.x;
  if (j < HD) {
    float acc = 0.f;
    for (int l = 0; l < L; ++l) acc += emb[(size_t)codes[t * L + l] * HD + j];
    s[j] = acc;
  }
  __syncthreads();
  const int g = j;
  float acc = bih[g];
  const float* wr = wih + (size_t)g * HD;
  for (int k = 0; k < HD; k += 4) {
    float4 w4 = *(const float4*)(wr + k);
    acc = fmaf(w4.x, s[k], acc);
    acc = fmaf(w4.y, s[k + 1], acc);
    acc = fmaf(w4.z, s[k + 2], acc);
    acc = fmaf(w4.w, s[k + 3], acc);
  }
  GI[((size_t)b * TT + t) * 768 + g] = acc;
}

// K2: sequential GRU. 98KB LDS GI-stage forces 1 block/CU (12 waves = 3/SIMD)
// => ~168 VGPR budget; whh f16 chunks held in 128 VGPRs, asm-pinned so the
// compiler can't rematerialize the loads inside the t-loop.
__global__ __launch_bounds__(768, 3) void k2_gru(
    const float* __restrict__ GI, const h8* __restrict__ wt,
    const float* __restrict__ bhh_d, const float* __restrict__ bhh_p,
    float* __restrict__ feats)
{
  const int b = blockIdx.x, g = threadIdx.x;
  const float* gi = GI + (size_t)b * TT * 768;
  const float* bhh = b ? bhh_p : bhh_d;

  __shared__ float GIs[TT * 768];   // 98304 B  (forces 1 block/CU)
  __shared__ h8 hh8[32];            // h as packed f16 (512 B)
  __shared__ float ghs[768];        // 3072 B

  // stage all gate inputs into LDS (coalesced float4)
  {
    const float4* s4 = (const float4*)gi;
    float4* d4 = (float4*)GIs;
#pragma unroll
    for (int i = 0; i < 8; ++i) d4[g + 768 * i] = s4[g + 768 * i];
  }

  // load this row's whh into registers (transposed layout -> coalesced)
  h2v w[128];
  {
    const h8* wrow = wt + (size_t)b * 32 * 768 + g;
#pragma unroll
    for (int i = 0; i < 32; ++i) {
      union { h8 v; h2v p[4]; } u;
      u.v = wrow[(size_t)i * 768];
      w[4 * i + 0] = u.p[0];
      w[4 * i + 1] = u.p[1];
      w[4 * i + 2] = u.p[2];
      w[4 * i + 3] = u.p[3];
    }
  }
  // pin: make each weight's origin opaque so it cannot be re-loaded per step
#pragma unroll
  for (int i = 0; i < 128; ++i) {
    float tmp = __builtin_bit_cast(float, w[i]);
    asm volatile("" : "+v"(tmp));
    w[i] = __builtin_bit_cast(h2v, tmp);
  }

  const float bh = bhh[g];
  float hreg = 0.f;
  if (g < HD) ((_Float16*)hh8)[g] = (_Float16)0.f;
  __syncthreads();

  for (int t = 0; t < TT; ++t) {
    float d0 = 0.f, d1 = 0.f, d2 = 0.f, d3 = 0.f;
#pragma unroll
    for (int i = 0; i < 32; ++i) {
      union { h8 v; h2v p[4]; } u;
      u.v = hh8[i];
      d0 = fdot2(w[4 * i + 0], u.p[0], d0);
      d1 = fdot2(w[4 * i + 1], u.p[1], d1);
      d2 = fdot2(w[4 * i + 2], u.p[2], d2);
      d3 = fdot2(w[4 * i + 3], u.p[3], d3);
    }
    ghs[g] = (d0 + d1) + (d2 + d3) + bh;
    __syncthreads();
    if (g < HD) {
      const float* git = GIs + t * 768;
      float ir = git[g], iz = git[HD + g], inn = git[2 * HD + g];
      float hr = ghs[g], hz = ghs[HD + g], hn = ghs[2 * HD + g];
      float r = 1.f / (1.f + __expf(-(ir + hr)));
      float z = 1.f / (1.f + __expf(-(iz + hz)));
      float n = tanhf(inn + r * hn);
      hreg = (1.f - z) * n + z * hreg;
      ((_Float16*)hh8)[g] = (_Float16)hreg;
      feats[(size_t)t * 512 + b * HD + g] = hreg;
    }
    __syncthreads();
  }
}

// K2b: queries[t,j] = q_b[j] + sum_k relu(feats[t,k]) * q_w[k,j]
__global__ __launch_bounds__(256) void k2b_queries(
    const float* __restrict__ feats, const float* __restrict__ q_w,
    const float* __restrict__ q_b, float* __restrict__ queries)
{
  const int t = blockIdx.x, j = threadIdx.x;
  __shared__ float f[512];
  f[j] = fmaxf(feats[(size_t)t * 512 + j], 0.f);
  f[j + 256] = fmaxf(feats[(size_t)t * 512 + 256 + j], 0.f);
  __syncthreads();
  float acc = q_b[j];
  for (int k = 0; k < 512; ++k) acc = fmaf(f[k], q_w[(size_t)k * HD + j], acc);
  queries[(size_t)t * HD + j] = acc;
}

// K3: stream one adj row per block; extract sparse (col,val) deterministically,
// and compute h1[row,:] = relu(sum val * w1[col,:] + b1).
__global__ __launch_bounds__(256) void k3_scan(
    const float* __restrict__ adj_e, const float* __restrict__ adj_d,
    const float* __restrict__ w1_e, const float* __restrict__ b1_e,
    const float* __restrict__ w1_d, const float* __restrict__ b1_d,
    float* __restrict__ h1, int* __restrict__ cnt_g,
    int* __restrict__ cols_g, float* __restrict__ vals_g)
{
  const int r = blockIdx.x, b = blockIdx.y, j = threadIdx.x;
  const float* adj = (b ? adj_d : adj_e) + (size_t)r * MV;
  const float* w1 = b ? w1_d : w1_e;
  const float* b1 = b ? b1_d : b1_e;

  __shared__ int pA[256], pB[256];
  __shared__ int scols[MAXNZ];
  __shared__ float svals[MAXNZ];

  const float4* row4 = (const float4*)adj;
  float4 v0 = row4[0 * 256 + j];
  float4 v1 = row4[1 * 256 + j];
  float4 v2 = row4[2 * 256 + j];
  float4 v3 = row4[3 * 256 + j];
  int cl = 0;
  cl += (v0.x != 0.f) + (v0.y != 0.f) + (v0.z != 0.f) + (v0.w != 0.f);
  cl += (v1.x != 0.f) + (v1.y != 0.f) + (v1.z != 0.f) + (v1.w != 0.f);
  cl += (v2.x != 0.f) + (v2.y != 0.f) + (v2.z != 0.f) + (v2.w != 0.f);
  cl += (v3.x != 0.f) + (v3.y != 0.f) + (v3.z != 0.f) + (v3.w != 0.f);

  pA[j] = cl;
  __syncthreads();
  int* src = pA; int* dst = pB;
  for (int ofs = 1; ofs < 256; ofs <<= 1) {
    dst[j] = src[j] + (j >= ofs ? src[j - ofs] : 0);
    __syncthreads();
    int* tmp = src; src = dst; dst = tmp;
  }
  const int total = src[255];
  int pos = src[j] - cl;  // exclusive prefix

#define EMIT(VV, CI, CE)                                        \
  { float val = (VV);                                           \
    if (val != 0.f) { if (pos < MAXNZ) { scols[pos] = (CI) * 1024 + 4 * j + (CE); svals[pos] = val; } ++pos; } }
  EMIT(v0.x, 0, 0) EMIT(v0.y, 0, 1) EMIT(v0.z, 0, 2) EMIT(v0.w, 0, 3)
  EMIT(v1.x, 1, 0) EMIT(v1.y, 1, 1) EMIT(v1.z, 1, 2) EMIT(v1.w, 1, 3)
  EMIT(v2.x, 2, 0) EMIT(v2.y, 2, 1) EMIT(v2.z, 2, 2) EMIT(v2.w, 2, 3)
  EMIT(v3.x, 3, 0) EMIT(v3.y, 3, 1) EMIT(v3.z, 3, 2) EMIT(v3.w, 3, 3)
#undef EMIT
  __syncthreads();

  const int n = total > MAXNZ ? MAXNZ : total;
  float acc = b1[j];
  for (int k = 0; k < n; ++k)
    acc = fmaf(svals[k], w1[(size_t)scols[k] * HD + j], acc);

  const size_t rowg = (size_t)b * MV + r;
  h1[rowg * HD + j] = fmaxf(acc, 0.f);
  if (j == 0) cnt_g[rowg] = n;
  if (j < n) {
    cols_g[rowg * MAXNZ + j] = scols[j];
    vals_g[rowg * MAXNZ + j] = svals[j];
  }
}

// K4: z = h1 @ w2  (per matrix), 16 rows per block, float4 LDS tile reads
__global__ __launch_bounds__(256) void k4_z(
    const float* __restrict__ h1, const float* __restrict__ w2_e,
    const float* __restrict__ w2_d, float* __restrict__ zz)
{
  const int blk = blockIdx.x, b = blockIdx.y, j = threadIdx.x;
  const float* w2 = b ? w2_d : w2_e;
  const float* h1b = h1 + (size_t)b * MV * HD + (size_t)blk * 16 * HD;
  __shared__ float tile[16][HD];
  for (int r = 0; r < 16; ++r) tile[r][j] = h1b[r * HD + j];
  __syncthreads();
  float acc[16];
#pragma unroll
  for (int r = 0; r < 16; ++r) acc[r] = 0.f;
  for (int k = 0; k < HD; k += 4) {
    float wa = w2[(size_t)(k + 0) * HD + j];
    float wb = w2[(size_t)(k + 1) * HD + j];
    float wc = w2[(size_t)(k + 2) * HD + j];
    float wd = w2[(size_t)(k + 3) * HD + j];
#pragma unroll
    for (int r = 0; r < 16; ++r) {
      float4 tv = *(const float4*)&tile[r][k];
      acc[r] = fmaf(tv.x, wa, acc[r]);
      acc[r] = fmaf(tv.y, wb, acc[r]);
      acc[r] = fmaf(tv.z, wc, acc[r]);
      acc[r] = fmaf(tv.w, wd, acc[r]);
    }
  }
  float* zb = zz + (size_t)b * MV * HD + (size_t)blk * 16 * HD;
  for (int r = 0; r < 16; ++r) zb[r * HD + j] = acc[r];
}

// K5: prior[r,:] = (sparse_ehr(r)@z_e + b2_e) - inter*(sparse_ddi(r)@z_d + b2_d);
//     s1[r] = query . prior[r,:]
__global__ __launch_bounds__(256) void k5_prior(
    const float* __restrict__ zz, const int* __restrict__ cnt_g,
    const int* __restrict__ cols_g, const float* __restrict__ vals_g,
    const float* __restrict__ b2_e, const float* __restrict__ b2_d,
    const float* __restrict__ inter, const float* __restrict__ queries,
    float* __restrict__ prior, float* __restrict__ s1)
{
  const int r = blockIdx.x, j = threadIdx.x;
  __shared__ float red[256];
  float acc_e = b2_e[j];
  {
    const int ne = cnt_g[r];
    const int* ce = cols_g + (size_t)r * MAXNZ;
    const float* ve = vals_g + (size_t)r * MAXNZ;
    for (int k = 0; k < ne; ++k)
      acc_e = fmaf(ve[k], zz[(size_t)ce[k] * HD + j], acc_e);
  }
  float acc_d = b2_d[j];
  {
    const int nd = cnt_g[MV + r];
    const int* cd = cols_g + (size_t)(MV + r) * MAXNZ;
    const float* vd = vals_g + (size_t)(MV + r) * MAXNZ;
    const float* zd = zz + (size_t)MV * HD;
    for (int k = 0; k < nd; ++k)
      acc_d = fmaf(vd[k], zd[(size_t)cd[k] * HD + j], acc_d);
  }
  const float pr = acc_e - inter[0] * acc_d;
  prior[(size_t)r * HD + j] = pr;
  red[j] = queries[31 * HD + j] * pr;
  __syncthreads();
  for (int s = 128; s > 0; s >>= 1) {
    if (j < s) red[j] += red[j + s];
    __syncthreads();
  }
  if (j == 0) s1[r] = red[0];
}

// K6a: w_emb = softmax(s1) over 4096; visit_w = softmax(query . queries[t<31])
__global__ __launch_bounds__(1024) void k6a_softmax(
    const float* __restrict__ s1, const float* __restrict__ queries,
    float* __restrict__ w_emb, float* __restrict__ visw)
{
  const int j = threadIdx.x;
  __shared__ float red[1024];
  __shared__ float s2[31];
  float m = -1e30f;
  for (int i = j; i < MV; i += 1024) m = fmaxf(m, s1[i]);
  red[j] = m;
  __syncthreads();
  for (int s = 512; s > 0; s >>= 1) {
    if (j < s) red[j] = fmaxf(red[j], red[j + s]);
    __syncthreads();
  }
  const float mx = red[0];
  __syncthreads();
  float sum = 0.f;
  for (int i = j; i < MV; i += 1024) sum += __expf(s1[i] - mx);
  red[j] = sum;
  __syncthreads();
  for (int s = 512; s > 0; s >>= 1) {
    if (j < s) red[j] += red[j + s];
    __syncthreads();
  }
  const float inv = 1.f / red[0];
  for (int i = j; i < MV; i += 1024) w_emb[i] = __expf(s1[i] - mx) * inv;

  if (j < 31) {
    float acc = 0.f;
    for (int k = 0; k < HD; ++k)
      acc = fmaf(queries[31 * HD + k], queries[(size_t)j * HD + k], acc);
    s2[j] = acc;
  }
  __syncthreads();
  if (j == 0) {
    float mm = -1e30f;
    for (int t = 0; t < 31; ++t) mm = fmaxf(mm, s2[t]);
    float ss = 0.f;
    for (int t = 0; t < 31; ++t) ss += __expf(s2[t] - mm);
    const float is = 1.f / ss;
    for (int t = 0; t < 31; ++t) visw[t] = __expf(s2[t] - mm) * is;
  }
}

// K6b: wv[m] = sum_t visit_w[t] * [m in med_codes[t]]  (set semantics)
__global__ __launch_bounds__(1024) void k6b_wv(
    const int* __restrict__ med, const float* __restrict__ visw,
    float* __restrict__ wv)
{
  __shared__ int mc[31 * LM_];
  __shared__ float vw[31];
  const int j = threadIdx.x;
  if (j < 31 * LM_) mc[j] = med[j];
  if (j < 31) vw[j] = visw[j];
  __syncthreads();
  const int m = blockIdx.x * 1024 + j;
  float acc = 0.f;
  for (int t = 0; t < 31; ++t) {
    bool found = false;
#pragma unroll
    for (int l = 0; l < LM_; ++l) found = found || (mc[t * LM_ + l] == m);
    if (found) acc += vw[t];
  }
  wv[m] = acc;
}

// K7: out[r,j] = w_emb[r]*(prior[r,:].Wa[:,j]) + wv[r]*(prior[r,:].Wb[:,j]) + proj_b[j]
__global__ __launch_bounds__(256) void k7_out(
    const float* __restrict__ prior, const float* __restrict__ w_emb,
    const float* __restrict__ wv, const float* __restrict__ proj_w,
    const float* __restrict__ proj_b, float* __restrict__ out)
{
  const int blk = blockIdx.x, j = threadIdx.x;
  const int r0 = blk * 16;
  __shared__ float tile[16][HD];
  __shared__ float we[16], wvv[16];
  for (int r = 0; r < 16; ++r) tile[r][j] = prior[(size_t)(r0 + r) * HD + j];
  if (j < 16) { we[j] = w_emb[r0 + j]; wvv[j] = wv[r0 + j]; }
  __syncthreads();
  float accA[16], accB[16];
#pragma unroll
  for (int r = 0; r < 16; ++r) { accA[r] = 0.f; accB[r] = 0.f; }
  for (int k = 0; k < HD; k += 4) {
    float wa0 = proj_w[(size_t)(k + 0) * HD + j];
    float wa1 = proj_w[(size_t)(k + 1) * HD + j];
    float wa2 = proj_w[(size_t)(k + 2) * HD + j];
    float wa3 = proj_w[(size_t)(k + 3) * HD + j];
    float wb0 = proj_w[(size_t)(k + 0 + HD) * HD + j];
    float wb1 = proj_w[(size_t)(k + 1 + HD) * HD + j];
    float wb2 = proj_w[(size_t)(k + 2 + HD) * HD + j];
    float wb3 = proj_w[(size_t)(k + 3 + HD) * HD + j];
#pragma unroll
    for (int r = 0; r < 16; ++r) {
      float4 tv = *(const float4*)&tile[r][k];
      accA[r] = fmaf(tv.x, wa0, accA[r]);
      accA[r] = fmaf(tv.y, wa1, accA[r]);
      accA[r] = fmaf(tv.z, wa2, accA[r]);
      accA[r] = fmaf(tv.w, wa3, accA[r]);
      accB[r] = fmaf(tv.x, wb0, accB[r]);
      accB[r] = fmaf(tv.y, wb1, accB[r]);
      accB[r] = fmaf(tv.z, wb2, accB[r]);
      accB[r] = fmaf(tv.w, wb3, accB[r]);
    }
  }
  const float pb = proj_b[j];
  for (int r = 0; r < 16; ++r)
    out[(size_t)(r0 + r) * HD + j] = we[r] * accA[r] + wvv[r] * accB[r] + pb;
}

extern "C" void kernel_launch(void* const* d_in, const int* in_sizes, int n_in,
                              void* d_out, int out_size, void* d_ws, size_t ws_size,
                              hipStream_t stream) {
  const int* diag_codes = (const int*)d_in[0];
  const int* proc_codes = (const int*)d_in[1];
  const int* med_codes  = (const int*)d_in[2];
  const float* diag_emb = (const float*)d_in[3];
  const float* proc_emb = (const float*)d_in[4];
  const float* wih_d = (const float*)d_in[5];
  const float* whh_d = (const float*)d_in[6];
  const float* bih_d = (const float*)d_in[7];
  const float* bhh_d = (const float*)d_in[8];
  const float* wih_p = (const float*)d_in[9];
  const float* whh_p = (const float*)d_in[10];
  const float* bih_p = (const float*)d_in[11];
  const float* bhh_p = (const float*)d_in[12];
  const float* q_w = (const float*)d_in[13];
  const float* q_b = (const float*)d_in[14];
  const float* adj_ehr = (const float*)d_in[15];
  const float* adj_ddi = (const float*)d_in[16];
  const float* w1_ehr = (const float*)d_in[17];
  const float* b1_ehr = (const float*)d_in[18];
  const float* w2_ehr = (const float*)d_in[19];
  const float* b2_ehr = (const float*)d_in[20];
  const float* w1_ddi = (const float*)d_in[21];
  const float* b1_ddi = (const float*)d_in[22];
  const float* w2_ddi = (const float*)d_in[23];
  const float* b2_ddi = (const float*)d_in[24];
  const float* inter = (const float*)d_in[25];
  const float* proj_w = (const float*)d_in[26];
  const float* proj_b = (const float*)d_in[27];
  float* out = (float*)d_out;

  float* ws = (float*)d_ws;
  size_t off = 0;
  float* GI      = ws + off; off += 2 * TT * 768;        // 49152
  float* feats   = ws + off; off += TT * 512;            // 16384
  float* queries = ws + off; off += TT * HD;             // 8192
  float* h1      = ws + off; off += 2 * (size_t)MV * HD; // 2M
  float* zz      = ws + off; off += 2 * (size_t)MV * HD; // 2M
  float* prior   = ws + off; off += (size_t)MV * HD;     // 1M
  float* s1      = ws + off; off += MV;
  float* w_emb   = ws + off; off += MV;
  float* visw    = ws + off; off += 32;
  float* wv      = ws + off; off += MV;
  int*   cnt_g   = (int*)(ws + off); off += 2 * MV;
  int*   cols_g  = (int*)(ws + off); off += 2 * (size_t)MV * MAXNZ;
  float* vals_g  = ws + off; off += 2 * (size_t)MV * MAXNZ;
  h8*    wt      = (h8*)(ws + off); off += 2 * 32 * 768 * 4; // 786432 B
  (void)ws_size; (void)in_sizes; (void)n_in; (void)out_size;

  k0_cvt<<<dim3(32, 2), 768, 0, stream>>>(whh_d, whh_p, wt);
  k1_embed_gi<<<dim3(TT, 2), 768, 0, stream>>>(diag_codes, proc_codes, diag_emb,
      proc_emb, wih_d, bih_d, wih_p, bih_p, GI);
  k2_gru<<<2, 768, 0, stream>>>(GI, wt, bhh_d, bhh_p, feats);
  k2b_queries<<<TT, 256, 0, stream>>>(feats, q_w, q_b, queries);
  k3_scan<<<dim3(MV, 2), 256, 0, stream>>>(adj_ehr, adj_ddi, w1_ehr, b1_ehr,
      w1_ddi, b1_ddi, h1, cnt_g, cols_g, vals_g);
  k4_z<<<dim3(MV / 16, 2), 256, 0, stream>>>(h1, w2_ehr, w2_ddi, zz);
  k5_prior<<<MV, 256, 0, stream>>>(zz, cnt_g, cols_g, vals_g, b2_ehr, b2_ddi,
      inter, queries, prior, s1);
  k6a_softmax<<<1, 1024, 0, stream>>>(s1, queries, w_emb, visw);
  k6b_wv<<<MV / 1024, 1024, 0, stream>>>(med_codes, visw, wv);
  k7_out<<<MV / 16, 256, 0, stream>>>(prior, w_emb, wv, proj_w, proj_b, out);
}

// Round 4
// 227.424 us; speedup vs baseline: 1.2698x; 1.1120x over previous
//
#include <hip/hip_runtime.h>
#include <hip/hip_bf16.h>

// Sizes
#define HD   256
#define TT   32
#define MV   4096
#define LD_  24
#define LP_  12
#define LM_  20
#define MAXNZ 96

typedef _Float16 h2v __attribute__((ext_vector_type(2)));
typedef _Float16 h8  __attribute__((ext_vector_type(8)));

__device__ __forceinline__ float fdot2(h2v a, h2v b, float c) {
#if __has_builtin(__builtin_amdgcn_fdot2)
  return __builtin_amdgcn_fdot2(a, b, c, false);
#else
  return c + (float)a[0] * (float)b[0] + (float)a[1] * (float)b[1];
#endif
}

// K0: whh (f32, 768x256 row-major) -> f16, transposed chunk layout:
// wt[b][i][g] = h8 of whh[b][g][8i..8i+7]  (i in [0,32), g in [0,768))
__global__ __launch_bounds__(768) void k0_cvt(
    const float* __restrict__ whh_d, const float* __restrict__ whh_p,
    h8* __restrict__ wt)
{
  const int i = blockIdx.x, b = blockIdx.y, g = threadIdx.x;
  const float* whh = b ? whh_p : whh_d;
  const float* src = whh + (size_t)g * HD + 8 * i;
  h8 v;
#pragma unroll
  for (int e = 0; e < 8; ++e) v[e] = (_Float16)src[e];
  wt[((size_t)b * 32 + i) * 768 + g] = v;
}

// K1: seq = sum of embedding rows; GI[b][t][g] = bih[g] + sum_k wih[g,k]*seq[k]
__global__ __launch_bounds__(768) void k1_embed_gi(
    const int* __restrict__ dc, const int* __restrict__ pc,
    const float* __restrict__ demb, const float* __restrict__ pemb,
    const float* __restrict__ wih_d, const float* __restrict__ bih_d,
    const float* __restrict__ wih_p, const float* __restrict__ bih_p,
    float* __restrict__ GI)
{
  const int t = blockIdx.x, b = blockIdx.y;
  const int* codes = b ? pc : dc;
  const int L = b ? LP_ : LD_;
  const float* emb = b ? pemb : demb;
  const float* wih = b ? wih_p : wih_d;
  const float* bih = b ? bih_p : bih_d;
  __shared__ float s[HD];
  const int j = threadIdx.x;
  if (j < HD) {
    float acc = 0.f;
    for (int l = 0; l < L; ++l) acc += emb[(size_t)codes[t * L + l] * HD + j];
    s[j] = acc;
  }
  __syncthreads();
  const int g = j;
  float acc = bih[g];
  const float* wr = wih + (size_t)g * HD;
  for (int k = 0; k < HD; k += 4) {
    float4 w4 = *(const float4*)(wr + k);
    acc = fmaf(w4.x, s[k], acc);
    acc = fmaf(w4.y, s[k + 1], acc);
    acc = fmaf(w4.z, s[k + 2], acc);
    acc = fmaf(w4.w, s[k + 3], acc);
  }
  GI[((size_t)b * TT + t) * 768 + g] = acc;
}

// K2: sequential GRU. 98KB LDS GI-stage forces 1 block/CU (12 waves = 3/SIMD)
// => ~168 VGPR budget; whh f16 chunks held in 128 VGPRs, asm-pinned.
__global__ __launch_bounds__(768, 3) void k2_gru(
    const float* __restrict__ GI, const h8* __restrict__ wt,
    const float* __restrict__ bhh_d, const float* __restrict__ bhh_p,
    float* __restrict__ feats)
{
  const int b = blockIdx.x, g = threadIdx.x;
  const float* gi = GI + (size_t)b * TT * 768;
  const float* bhh = b ? bhh_p : bhh_d;

  __shared__ float GIs[TT * 768];   // 98304 B  (forces 1 block/CU)
  __shared__ h8 hh8[32];            // h as packed f16 (512 B)
  __shared__ float ghs[768];        // 3072 B

  {
    const float4* s4 = (const float4*)gi;
    float4* d4 = (float4*)GIs;
#pragma unroll
    for (int i = 0; i < 8; ++i) d4[g + 768 * i] = s4[g + 768 * i];
  }

  h2v w[128];
  {
    const h8* wrow = wt + (size_t)b * 32 * 768 + g;
#pragma unroll
    for (int i = 0; i < 32; ++i) {
      union { h8 v; h2v p[4]; } u;
      u.v = wrow[(size_t)i * 768];
      w[4 * i + 0] = u.p[0];
      w[4 * i + 1] = u.p[1];
      w[4 * i + 2] = u.p[2];
      w[4 * i + 3] = u.p[3];
    }
  }
#pragma unroll
  for (int i = 0; i < 128; ++i) {
    float tmp = __builtin_bit_cast(float, w[i]);
    asm volatile("" : "+v"(tmp));
    w[i] = __builtin_bit_cast(h2v, tmp);
  }

  const float bh = bhh[g];
  float hreg = 0.f;
  if (g < HD) ((_Float16*)hh8)[g] = (_Float16)0.f;
  __syncthreads();

  for (int t = 0; t < TT; ++t) {
    float d0 = 0.f, d1 = 0.f, d2 = 0.f, d3 = 0.f;
#pragma unroll
    for (int i = 0; i < 32; ++i) {
      union { h8 v; h2v p[4]; } u;
      u.v = hh8[i];
      d0 = fdot2(w[4 * i + 0], u.p[0], d0);
      d1 = fdot2(w[4 * i + 1], u.p[1], d1);
      d2 = fdot2(w[4 * i + 2], u.p[2], d2);
      d3 = fdot2(w[4 * i + 3], u.p[3], d3);
    }
    ghs[g] = (d0 + d1) + (d2 + d3) + bh;
    __syncthreads();
    if (g < HD) {
      const float* git = GIs + t * 768;
      float ir = git[g], iz = git[HD + g], inn = git[2 * HD + g];
      float hr = ghs[g], hz = ghs[HD + g], hn = ghs[2 * HD + g];
      float r = 1.f / (1.f + __expf(-(ir + hr)));
      float z = 1.f / (1.f + __expf(-(iz + hz)));
      float n = tanhf(inn + r * hn);
      hreg = (1.f - z) * n + z * hreg;
      ((_Float16*)hh8)[g] = (_Float16)hreg;
      feats[(size_t)t * 512 + b * HD + g] = hreg;
    }
    __syncthreads();
  }
}

// K2b: queries[t,j] = q_b[j] + sum_k relu(feats[t,k]) * q_w[k,j]
__global__ __launch_bounds__(256) void k2b_queries(
    const float* __restrict__ feats, const float* __restrict__ q_w,
    const float* __restrict__ q_b, float* __restrict__ queries)
{
  const int t = blockIdx.x, j = threadIdx.x;
  __shared__ float f[512];
  f[j] = fmaxf(feats[(size_t)t * 512 + j], 0.f);
  f[j + 256] = fmaxf(feats[(size_t)t * 512 + 256 + j], 0.f);
  __syncthreads();
  float acc = q_b[j];
  for (int k = 0; k < 512; ++k) acc = fmaf(f[k], q_w[(size_t)k * HD + j], acc);
  queries[(size_t)t * HD + j] = acc;
}

// K3: stream one adj row per block; extract sparse (col,val) deterministically,
// and compute h1[row,:] = relu(sum val * w1[col,:] + b1).
__global__ __launch_bounds__(256) void k3_scan(
    const float* __restrict__ adj_e, const float* __restrict__ adj_d,
    const float* __restrict__ w1_e, const float* __restrict__ b1_e,
    const float* __restrict__ w1_d, const float* __restrict__ b1_d,
    float* __restrict__ h1, int* __restrict__ cnt_g,
    int* __restrict__ cols_g, float* __restrict__ vals_g)
{
  const int r = blockIdx.x, b = blockIdx.y, j = threadIdx.x;
  const float* adj = (b ? adj_d : adj_e) + (size_t)r * MV;
  const float* w1 = b ? w1_d : w1_e;
  const float* b1 = b ? b1_d : b1_e;

  __shared__ int pA[256], pB[256];
  __shared__ int scols[MAXNZ];
  __shared__ float svals[MAXNZ];

  const float4* row4 = (const float4*)adj;
  float4 v0 = row4[0 * 256 + j];
  float4 v1 = row4[1 * 256 + j];
  float4 v2 = row4[2 * 256 + j];
  float4 v3 = row4[3 * 256 + j];
  int cl = 0;
  cl += (v0.x != 0.f) + (v0.y != 0.f) + (v0.z != 0.f) + (v0.w != 0.f);
  cl += (v1.x != 0.f) + (v1.y != 0.f) + (v1.z != 0.f) + (v1.w != 0.f);
  cl += (v2.x != 0.f) + (v2.y != 0.f) + (v2.z != 0.f) + (v2.w != 0.f);
  cl += (v3.x != 0.f) + (v3.y != 0.f) + (v3.z != 0.f) + (v3.w != 0.f);

  pA[j] = cl;
  __syncthreads();
  int* src = pA; int* dst = pB;
  for (int ofs = 1; ofs < 256; ofs <<= 1) {
    dst[j] = src[j] + (j >= ofs ? src[j - ofs] : 0);
    __syncthreads();
    int* tmp = src; src = dst; dst = tmp;
  }
  const int total = src[255];
  int pos = src[j] - cl;  // exclusive prefix

#define EMIT(VV, CI, CE)                                        \
  { float val = (VV);                                           \
    if (val != 0.f) { if (pos < MAXNZ) { scols[pos] = (CI) * 1024 + 4 * j + (CE); svals[pos] = val; } ++pos; } }
  EMIT(v0.x, 0, 0) EMIT(v0.y, 0, 1) EMIT(v0.z, 0, 2) EMIT(v0.w, 0, 3)
  EMIT(v1.x, 1, 0) EMIT(v1.y, 1, 1) EMIT(v1.z, 1, 2) EMIT(v1.w, 1, 3)
  EMIT(v2.x, 2, 0) EMIT(v2.y, 2, 1) EMIT(v2.z, 2, 2) EMIT(v2.w, 2, 3)
  EMIT(v3.x, 3, 0) EMIT(v3.y, 3, 1) EMIT(v3.z, 3, 2) EMIT(v3.w, 3, 3)
#undef EMIT
  __syncthreads();

  const int n = total > MAXNZ ? MAXNZ : total;
  float acc = b1[j];
  for (int k = 0; k < n; ++k)
    acc = fmaf(svals[k], w1[(size_t)scols[k] * HD + j], acc);

  const size_t rowg = (size_t)b * MV + r;
  h1[rowg * HD + j] = fmaxf(acc, 0.f);
  if (j == 0) cnt_g[rowg] = n;
  if (j < n) {
    cols_g[rowg * MAXNZ + j] = scols[j];
    vals_g[rowg * MAXNZ + j] = svals[j];
  }
}

// K4: z = h1 @ w2. 8 rows/block, 512 threads: half 0 -> k in [0,128),
// half 1 -> k in [128,256); LDS partial combine. grid (512,2) = 4 blocks/CU.
__global__ __launch_bounds__(512) void k4_z(
    const float* __restrict__ h1, const float* __restrict__ w2_e,
    const float* __restrict__ w2_d, float* __restrict__ zz)
{
  const int blk = blockIdx.x, b = blockIdx.y;
  const int t = threadIdx.x;
  const int j = t & 255, half = t >> 8;
  const float* w2 = b ? w2_d : w2_e;
  const float* h1b = h1 + (size_t)b * MV * HD + (size_t)blk * 8 * HD;
  __shared__ float tile[8][HD];
  __shared__ float part[8][HD];
  {
    float4* t4 = (float4*)tile;
    const float4* s4 = (const float4*)h1b;
    t4[t] = s4[t];
  }
  __syncthreads();
  float acc[8];
#pragma unroll
  for (int r = 0; r < 8; ++r) acc[r] = 0.f;
  const int k0 = half * 128;
  for (int k = k0; k < k0 + 128; k += 4) {
    float wa = w2[(size_t)(k + 0) * HD + j];
    float wb = w2[(size_t)(k + 1) * HD + j];
    float wc = w2[(size_t)(k + 2) * HD + j];
    float wd = w2[(size_t)(k + 3) * HD + j];
#pragma unroll
    for (int r = 0; r < 8; ++r) {
      float4 tv = *(const float4*)&tile[r][k];
      acc[r] = fmaf(tv.x, wa, acc[r]);
      acc[r] = fmaf(tv.y, wb, acc[r]);
      acc[r] = fmaf(tv.z, wc, acc[r]);
      acc[r] = fmaf(tv.w, wd, acc[r]);
    }
  }
  if (half == 1) {
#pragma unroll
    for (int r = 0; r < 8; ++r) part[r][j] = acc[r];
  }
  __syncthreads();
  if (half == 0) {
    float* zb = zz + (size_t)b * MV * HD + (size_t)blk * 8 * HD;
#pragma unroll
    for (int r = 0; r < 8; ++r) zb[r * HD + j] = acc[r] + part[r][j];
  }
}

// K5: prior[r,:] = (sparse_ehr(r)@z_e + b2_e) - inter*(sparse_ddi(r)@z_d + b2_d);
//     s1[r] = query . prior[r,:]
__global__ __launch_bounds__(256) void k5_prior(
    const float* __restrict__ zz, const int* __restrict__ cnt_g,
    const int* __restrict__ cols_g, const float* __restrict__ vals_g,
    const float* __restrict__ b2_e, const float* __restrict__ b2_d,
    const float* __restrict__ inter, const float* __restrict__ queries,
    float* __restrict__ prior, float* __restrict__ s1)
{
  const int r = blockIdx.x, j = threadIdx.x;
  __shared__ float red[256];
  float acc_e = b2_e[j];
  {
    const int ne = cnt_g[r];
    const int* ce = cols_g + (size_t)r * MAXNZ;
    const float* ve = vals_g + (size_t)r * MAXNZ;
    for (int k = 0; k < ne; ++k)
      acc_e = fmaf(ve[k], zz[(size_t)ce[k] * HD + j], acc_e);
  }
  float acc_d = b2_d[j];
  {
    const int nd = cnt_g[MV + r];
    const int* cd = cols_g + (size_t)(MV + r) * MAXNZ;
    const float* vd = vals_g + (size_t)(MV + r) * MAXNZ;
    const float* zd = zz + (size_t)MV * HD;
    for (int k = 0; k < nd; ++k)
      acc_d = fmaf(vd[k], zd[(size_t)cd[k] * HD + j], acc_d);
  }
  const float pr = acc_e - inter[0] * acc_d;
  prior[(size_t)r * HD + j] = pr;
  red[j] = queries[31 * HD + j] * pr;
  __syncthreads();
  for (int s = 128; s > 0; s >>= 1) {
    if (j < s) red[j] += red[j + s];
    __syncthreads();
  }
  if (j == 0) s1[r] = red[0];
}

// K6a: w_emb = softmax(s1) over 4096; visit_w = softmax(query . queries[t<31])
__global__ __launch_bounds__(1024) void k6a_softmax(
    const float* __restrict__ s1, const float* __restrict__ queries,
    float* __restrict__ w_emb, float* __restrict__ visw)
{
  const int j = threadIdx.x;
  __shared__ float red[1024];
  __shared__ float s2[31];
  float m = -1e30f;
  for (int i = j; i < MV; i += 1024) m = fmaxf(m, s1[i]);
  red[j] = m;
  __syncthreads();
  for (int s = 512; s > 0; s >>= 1) {
    if (j < s) red[j] = fmaxf(red[j], red[j + s]);
    __syncthreads();
  }
  const float mx = red[0];
  __syncthreads();
  float sum = 0.f;
  for (int i = j; i < MV; i += 1024) sum += __expf(s1[i] - mx);
  red[j] = sum;
  __syncthreads();
  for (int s = 512; s > 0; s >>= 1) {
    if (j < s) red[j] += red[j + s];
    __syncthreads();
  }
  const float inv = 1.f / red[0];
  for (int i = j; i < MV; i += 1024) w_emb[i] = __expf(s1[i] - mx) * inv;

  if (j < 31) {
    float acc = 0.f;
    for (int k = 0; k < HD; ++k)
      acc = fmaf(queries[31 * HD + k], queries[(size_t)j * HD + k], acc);
    s2[j] = acc;
  }
  __syncthreads();
  if (j == 0) {
    float mm = -1e30f;
    for (int t = 0; t < 31; ++t) mm = fmaxf(mm, s2[t]);
    float ss = 0.f;
    for (int t = 0; t < 31; ++t) ss += __expf(s2[t] - mm);
    const float is = 1.f / ss;
    for (int t = 0; t < 31; ++t) visw[t] = __expf(s2[t] - mm) * is;
  }
}

// K6b: wv[m] = sum_t visit_w[t] * [m in med_codes[t]]  (set semantics)
__global__ __launch_bounds__(1024) void k6b_wv(
    const int* __restrict__ med, const float* __restrict__ visw,
    float* __restrict__ wv)
{
  __shared__ int mc[31 * LM_];
  __shared__ float vw[31];
  const int j = threadIdx.x;
  if (j < 31 * LM_) mc[j] = med[j];
  if (j < 31) vw[j] = visw[j];
  __syncthreads();
  const int m = blockIdx.x * 1024 + j;
  float acc = 0.f;
  for (int t = 0; t < 31; ++t) {
    bool found = false;
#pragma unroll
    for (int l = 0; l < LM_; ++l) found = found || (mc[t * LM_ + l] == m);
    if (found) acc += vw[t];
  }
  wv[m] = acc;
}

// K7: 8 rows/block, 512 threads: half 0 accumulates prior@Wa, half 1 prior@Wb
// (proj_w rows 256..511); LDS partial combine:
// out = we*A + wv*B + proj_b. grid 512 = 2 blocks/CU.
__global__ __launch_bounds__(512) void k7_out(
    const float* __restrict__ prior, const float* __restrict__ w_emb,
    const float* __restrict__ wv, const float* __restrict__ proj_w,
    const float* __restrict__ proj_b, float* __restrict__ out)
{
  const int blk = blockIdx.x;
  const int t = threadIdx.x;
  const int j = t & 255, half = t >> 8;
  const int r0 = blk * 8;
  __shared__ float tile[8][HD];
  __shared__ float part[8][HD];
  __shared__ float we[8], wvv[8];
  {
    float4* t4 = (float4*)tile;
    const float4* s4 = (const float4*)(prior + (size_t)r0 * HD);
    t4[t] = s4[t];
  }
  if (t < 8) { we[t] = w_emb[r0 + t]; wvv[t] = wv[r0 + t]; }
  __syncthreads();
  const float* wmat = proj_w + (size_t)half * HD * HD;  // half0: Wa, half1: Wb
  float acc[8];
#pragma unroll
  for (int r = 0; r < 8; ++r) acc[r] = 0.f;
  for (int k = 0; k < HD; k += 4) {
    float wa = wmat[(size_t)(k + 0) * HD + j];
    float wb = wmat[(size_t)(k + 1) * HD + j];
    float wc = wmat[(size_t)(k + 2) * HD + j];
    float wd = wmat[(size_t)(k + 3) * HD + j];
#pragma unroll
    for (int r = 0; r < 8; ++r) {
      float4 tv = *(const float4*)&tile[r][k];
      acc[r] = fmaf(tv.x, wa, acc[r]);
      acc[r] = fmaf(tv.y, wb, acc[r]);
      acc[r] = fmaf(tv.z, wc, acc[r]);
      acc[r] = fmaf(tv.w, wd, acc[r]);
    }
  }
  if (half == 1) {
#pragma unroll
    for (int r = 0; r < 8; ++r) part[r][j] = acc[r];
  }
  __syncthreads();
  if (half == 0) {
    const float pb = proj_b[j];
#pragma unroll
    for (int r = 0; r < 8; ++r)
      out[(size_t)(r0 + r) * HD + j] = we[r] * acc[r] + wvv[r] * part[r][j] + pb;
  }
}

extern "C" void kernel_launch(void* const* d_in, const int* in_sizes, int n_in,
                              void* d_out, int out_size, void* d_ws, size_t ws_size,
                              hipStream_t stream) {
  const int* diag_codes = (const int*)d_in[0];
  const int* proc_codes = (const int*)d_in[1];
  const int* med_codes  = (const int*)d_in[2];
  const float* diag_emb = (const float*)d_in[3];
  const float* proc_emb = (const float*)d_in[4];
  const float* wih_d = (const float*)d_in[5];
  const float* whh_d = (const float*)d_in[6];
  const float* bih_d = (const float*)d_in[7];
  const float* bhh_d = (const float*)d_in[8];
  const float* wih_p = (const float*)d_in[9];
  const float* whh_p = (const float*)d_in[10];
  const float* bih_p = (const float*)d_in[11];
  const float* bhh_p = (const float*)d_in[12];
  const float* q_w = (const float*)d_in[13];
  const float* q_b = (const float*)d_in[14];
  const float* adj_ehr = (const float*)d_in[15];
  const float* adj_ddi = (const float*)d_in[16];
  const float* w1_ehr = (const float*)d_in[17];
  const float* b1_ehr = (const float*)d_in[18];
  const float* w2_ehr = (const float*)d_in[19];
  const float* b2_ehr = (const float*)d_in[20];
  const float* w1_ddi = (const float*)d_in[21];
  const float* b1_ddi = (const float*)d_in[22];
  const float* w2_ddi = (const float*)d_in[23];
  const float* b2_ddi = (const float*)d_in[24];
  const float* inter = (const float*)d_in[25];
  const float* proj_w = (const float*)d_in[26];
  const float* proj_b = (const float*)d_in[27];
  float* out = (float*)d_out;

  float* ws = (float*)d_ws;
  size_t off = 0;
  float* GI      = ws + off; off += 2 * TT * 768;        // 49152
  float* feats   = ws + off; off += TT * 512;            // 16384
  float* queries = ws + off; off += TT * HD;             // 8192
  float* h1      = ws + off; off += 2 * (size_t)MV * HD; // 2M
  float* zz      = ws + off; off += 2 * (size_t)MV * HD; // 2M
  float* prior   = ws + off; off += (size_t)MV * HD;     // 1M
  float* s1      = ws + off; off += MV;
  float* w_emb   = ws + off; off += MV;
  float* visw    = ws + off; off += 32;
  float* wv      = ws + off; off += MV;
  int*   cnt_g   = (int*)(ws + off); off += 2 * MV;
  int*   cols_g  = (int*)(ws + off); off += 2 * (size_t)MV * MAXNZ;
  float* vals_g  = ws + off; off += 2 * (size_t)MV * MAXNZ;
  h8*    wt      = (h8*)(ws + off); off += 2 * 32 * 768 * 4; // 786432 B
  (void)ws_size; (void)in_sizes; (void)n_in; (void)out_size;

  k0_cvt<<<dim3(32, 2), 768, 0, stream>>>(whh_d, whh_p, wt);
  k1_embed_gi<<<dim3(TT, 2), 768, 0, stream>>>(diag_codes, proc_codes, diag_emb,
      proc_emb, wih_d, bih_d, wih_p, bih_p, GI);
  k2_gru<<<2, 768, 0, stream>>>(GI, wt, bhh_d, bhh_p, feats);
  k2b_queries<<<TT, 256, 0, stream>>>(feats, q_w, q_b, queries);
  k3_scan<<<dim3(MV, 2), 256, 0, stream>>>(adj_ehr, adj_ddi, w1_ehr, b1_ehr,
      w1_ddi, b1_ddi, h1, cnt_g, cols_g, vals_g);
  k4_z<<<dim3(MV / 8, 2), 512, 0, stream>>>(h1, w2_ehr, w2_ddi, zz);
  k5_prior<<<MV, 256, 0, stream>>>(zz, cnt_g, cols_g, vals_g, b2_ehr, b2_ddi,
      inter, queries, prior, s1);
  k6a_softmax<<<1, 1024, 0, stream>>>(s1, queries, w_emb, visw);
  k6b_wv<<<MV / 1024, 1024, 0, stream>>>(med_codes, visw, wv);
  k7_out<<<MV / 8, 512, 0, stream>>>(prior, w_emb, wv, proj_w, proj_b, out);
}